// Round 16
// baseline (697.410 us; speedup 1.0000x reference)
//
#include <hip/hip_runtime.h>
#include <math.h>

#define EPSBN 1e-5f

typedef _Float16 f16;
typedef _Float16 f16x8 __attribute__((ext_vector_type(8)));
typedef _Float16 f16x4 __attribute__((ext_vector_type(4)));
typedef _Float16 f16x2 __attribute__((ext_vector_type(2)));
typedef float f32x4 __attribute__((ext_vector_type(4)));

static __device__ inline f16x8 h8zero() {
    f16x8 v;
#pragma unroll
    for (int j = 0; j < 8; j++) v[j] = (f16)0.f;
    return v;
}

// ---------------------------------------------------------------------------
// MFMA f16 GEMM. BM=64, BN=128, BK=64. 4 waves (2x2), wave tile 32x64.
// A operand read DIRECTLY from global in MFMA fragment layout (equivalent to
// the old LDS path: read-swizzle cancels staging pre-swizzle; per row the
// 8 lanes consume the full 128B segment -> no cache over-fetch; L1 shares
// across waves). B staged in LDS with 2-deep register pipeline (r11-proven:
// pre-swizzled source + linear write + swizzled read).
// Optional fused BN column sums via shfl+atomicAdd.
// MODE 0: out f16 NHWC; MODE 1: conv3x3-d1 (spatial hardcoded 64x64);
// MODE 2: out f32 CHW + bias.
// ---------------------------------------------------------------------------
template<int MODE>
__global__ __launch_bounds__(256)
void hgemm_k(const f16* __restrict__ Wh, const f16* __restrict__ act,
             void* __restrict__ outv, const float* __restrict__ bias,
             int M, int K, int N, int Cact, long actStride, long outStride,
             int IW, int IH, float* __restrict__ sums)
{
    const int b = blockIdx.z;
    const int n0 = blockIdx.x * 128, m0 = blockIdx.y * 64;
    const f16* actb = act + (long)b * actStride;
    __shared__ __align__(16) f16 Bs[2][128 * 64];
    const int tid = threadIdx.x;
    const int wave = tid >> 6, lane = tid & 63;
    const int wm = (wave >> 1) * 32, wn = (wave & 1) * 64;
    const int lr = lane & 15, lg = lane >> 4;
    f32x4 acc[2][4];
#pragma unroll
    for (int i = 0; i < 2; i++)
#pragma unroll
        for (int j = 0; j < 4; j++)
#pragma unroll
            for (int r = 0; r < 4; r++) acc[i][j][r] = 0.f;

    // A fragment base pointers (loop-invariant); invalid rows -> row 0 + zero.
    const f16* aptr[2]; bool aval[2];
#pragma unroll
    for (int i = 0; i < 2; i++) {
        int r = m0 + wm + i * 16 + lr;
        aval[i] = (r < M);
        aptr[i] = Wh + (long)(aval[i] ? r : 0) * K;
    }
    const int co[2] = { lg * 8, (4 + lg) * 8 };

    const int nt = K >> 6;           // EVEN for all shapes used
    f16x8 rbA[4], rbB[4];

    auto LOADA = [&](int t) {
        const int kt = t << 6;
#pragma unroll
        for (int u = 0; u < 4; u++) {
            int idx = u * 256 + tid;
            int row = idx >> 3, slot = idx & 7;
            int scol = (slot ^ (row & 7)) << 3;
            int n = n0 + row;
            if (MODE == 1) {
                int tap = kt >> 9;
                int kc = (kt & 511) + scol;
                int dy = tap / 3 - 1, dx = tap % 3 - 1;
                int yy = (n >> 6) + dy, xx = (n & 63) + dx;   // 64x64 spatial
                rbA[u] = (yy >= 0 && yy < 64 && xx >= 0 && xx < 64)
                        ? *(const f16x8*)&actb[(long)((yy << 6) + xx) * Cact + kc]
                        : h8zero();
            } else {
                rbA[u] = *(const f16x8*)&actb[(long)n * Cact + kt + scol];
            }
        }
    };
    auto LOADB = [&](int t) {
        const int kt = t << 6;
#pragma unroll
        for (int u = 0; u < 4; u++) {
            int idx = u * 256 + tid;
            int row = idx >> 3, slot = idx & 7;
            int scol = (slot ^ (row & 7)) << 3;
            int n = n0 + row;
            if (MODE == 1) {
                int tap = kt >> 9;
                int kc = (kt & 511) + scol;
                int dy = tap / 3 - 1, dx = tap % 3 - 1;
                int yy = (n >> 6) + dy, xx = (n & 63) + dx;
                rbB[u] = (yy >= 0 && yy < 64 && xx >= 0 && xx < 64)
                        ? *(const f16x8*)&actb[(long)((yy << 6) + xx) * Cact + kc]
                        : h8zero();
            } else {
                rbB[u] = *(const f16x8*)&actb[(long)n * Cact + kt + scol];
            }
        }
    };
    auto WRITEA = [&](int bufw) {
#pragma unroll
        for (int u = 0; u < 4; u++) {
            int idx = u * 256 + tid;
            int row = idx >> 3, slot = idx & 7;
            *(f16x8*)&Bs[bufw][(row * 8 + slot) * 8] = rbA[u];
        }
    };
    auto WRITEB = [&](int bufw) {
#pragma unroll
        for (int u = 0; u < 4; u++) {
            int idx = u * 256 + tid;
            int row = idx >> 3, slot = idx & 7;
            *(f16x8*)&Bs[bufw][(row * 8 + slot) * 8] = rbB[u];
        }
    };
    auto MFMA = [&](int bufr, int kt) {
#pragma unroll
        for (int s = 0; s < 2; s++) {
            f16x8 af[2], bf[4];
#pragma unroll
            for (int i = 0; i < 2; i++)
                af[i] = aval[i] ? *(const f16x8*)&aptr[i][kt + co[s]] : h8zero();
#pragma unroll
            for (int j = 0; j < 4; j++) {
                int r = wn + j * 16 + lr;
                bf[j] = *(const f16x8*)&Bs[bufr][(r * 8 + ((s * 4 + lg) ^ (r & 7))) * 8];
            }
#pragma unroll
            for (int i = 0; i < 2; i++)
#pragma unroll
                for (int j = 0; j < 4; j++)
                    acc[i][j] = __builtin_amdgcn_mfma_f32_16x16x32_f16(af[i], bf[j], acc[i][j], 0, 0, 0);
        }
    };

    LOADA(0); WRITEA(0); LOADB(1);
    __syncthreads();
    int buf = 0;
    for (int t = 0; t < nt; t += 2) {
        if (t + 2 < nt) LOADA(t + 2);
        MFMA(buf, t << 6);
        WRITEB(buf ^ 1);
        __syncthreads();
        buf ^= 1;
        if (t + 3 < nt) LOADB(t + 3);
        MFMA(buf, (t + 1) << 6);
        if (t + 2 < nt) WRITEA(buf ^ 1);
        __syncthreads();
        buf ^= 1;
    }

    if (MODE == 2) {
        float* outp = (float*)outv + (long)b * outStride;
#pragma unroll
        for (int i = 0; i < 2; i++)
#pragma unroll
            for (int j = 0; j < 4; j++) {
                int n = n0 + wn + j * 16 + lr;
#pragma unroll
                for (int r = 0; r < 4; r++) {
                    int m = m0 + wm + i * 16 + lg * 4 + r;
                    if (m < M) outp[(long)m * N + n] = acc[i][j][r] + bias[m];
                }
            }
    } else {
        f16* outp = (f16*)outv + (long)b * outStride;
#pragma unroll
        for (int i = 0; i < 2; i++)
#pragma unroll
            for (int j = 0; j < 4; j++) {
                int n = n0 + wn + j * 16 + lr;
                int mb = m0 + wm + i * 16 + lg * 4;
                if (mb < M) {
                    f16x4 hv;
#pragma unroll
                    for (int r = 0; r < 4; r++) hv[r] = (f16)acc[i][j][r];
                    *(f16x4*)&outp[(long)n * M + mb] = hv;
                }
            }
        if (sums) {
#pragma unroll
            for (int i = 0; i < 2; i++)
#pragma unroll
                for (int r = 0; r < 4; r++) {
                    int m = m0 + wm + i * 16 + lg * 4 + r;
                    float s = 0.f, s2 = 0.f;
#pragma unroll
                    for (int j = 0; j < 4; j++) {
                        float v = (float)(f16)acc[i][j][r];   // rounded value
                        s += v; s2 += v * v;
                    }
#pragma unroll
                    for (int msk = 1; msk < 16; msk <<= 1) {
                        s += __shfl_xor(s, msk);
                        s2 += __shfl_xor(s2, msk);
                    }
                    if (lr == 0 && m < M) {
                        atomicAdd(&sums[2 * m], s);
                        atomicAdd(&sums[2 * m + 1], s2);
                    }
                }
        }
    }
}

// CHW f32 -> NHWC f16 tiled transpose (C, HW multiples of 32)
__global__ __launch_bounds__(256)
void chw2nhwc_k(const float* __restrict__ in, f16* __restrict__ out, int C, int HW)
{
    int b = blockIdx.z;
    int l0 = blockIdx.x * 32, c0 = blockIdx.y * 32;
    __shared__ float t[32][33];
    int tx = threadIdx.x & 31, ty = threadIdx.x >> 5;
    const float* ib = in + (long)b * C * HW;
#pragma unroll
    for (int j = 0; j < 4; j++) {
        int c = c0 + ty + j * 8;
        t[ty + j * 8][tx] = ib[(long)c * HW + l0 + tx];
    }
    __syncthreads();
    f16* ob = out + (long)b * HW * C;
#pragma unroll
    for (int j = 0; j < 4; j++) {
        int l = l0 + ty + j * 8;
        ob[(long)l * C + c0 + tx] = (f16)t[tx][ty + j * 8];
    }
}

// flat f32 -> f16
__global__ void f2h_k(const float* __restrict__ src, f16* __restrict__ dst, long n)
{
    long i = blockIdx.x * 256L + threadIdx.x;
    if (i < n) dst[i] = (f16)src[i];
}

// w5 (O,C,3,3) f32 -> w5r[O][tap][C] f16  (K ordered taps-outer, c-inner)
__global__ void w5r_k(const float* __restrict__ src, f16* __restrict__ dst)
{
    long i = blockIdx.x * 256L + threadIdx.x;
    if (i >= 9L * 512 * 512) return;
    int c = (int)(i % 512); long t2 = i / 512;
    int t = (int)(t2 % 9); int o = (int)(t2 / 9);
    dst[i] = (f16)src[(long)o * 4608 + c * 9 + t];
}

__global__ void zero_k(float* __restrict__ p, int n)
{
    int i = blockIdx.x * 256 + threadIdx.x;
    if (i < n) p[i] = 0.f;
}

// apply BN (from raw sums) elementwise, f16 in/out, 8 elems/thread
__global__ __launch_bounds__(256)
void bnapply_k(f16* __restrict__ x, const float* __restrict__ mv,
               const float* __restrict__ g, const float* __restrict__ bta,
               int C, long total, float inv, int dorelu)
{
    long i8 = (blockIdx.x * 256L + threadIdx.x) * 8;
    if (i8 >= total) return;
    int c0 = (int)(i8 % C);
    f16x8 v = *(f16x8*)&x[i8];
#pragma unroll
    for (int j = 0; j < 8; j++) {
        int c = c0 + j;
        float m = mv[2 * c] * inv;
        float var = mv[2 * c + 1] * inv - m * m;
        float r = ((float)v[j] - m) * rsqrtf(var + EPSBN) * g[c] + bta[c];
        if (dorelu) r = fmaxf(r, 0.f);
        v[j] = (f16)r;
    }
    *(f16x8*)&x[i8] = v;
}

// bilinear upsample align_corners=True, NHWC f16, 8 channels/thread
__global__ __launch_bounds__(256)
void upsample_h8(const f16* __restrict__ in, f16* __restrict__ out,
                 int C8, int H, int W, int OH, int OW)
{
    long total = 2L * C8 * OH * OW;
    float ry = (float)(H - 1) / (float)(OH - 1);
    float rx = (float)(W - 1) / (float)(OW - 1);
    int C = C8 * 8;
    for (long i = blockIdx.x * 256L + threadIdx.x; i < total; i += (long)gridDim.x * 256) {
        int c8 = (int)(i % C8); long t = i / C8;
        int l = (int)(t % (OH * OW)); int bb = (int)(t / (OH * OW));
        int oy = l / OW, ox = l % OW;
        float fy = oy * ry, fx = ox * rx;
        int y0 = (int)fy, x0 = (int)fx;
        int y1 = min(y0 + 1, H - 1), x1 = min(x0 + 1, W - 1);
        float wy = fy - y0, wx = fx - x0;
        const f16* p = in + (long)bb * H * W * C + c8 * 8;
        f16x8 v00 = *(const f16x8*)&p[(long)(y0 * W + x0) * C];
        f16x8 v01 = *(const f16x8*)&p[(long)(y0 * W + x1) * C];
        f16x8 v10 = *(const f16x8*)&p[(long)(y1 * W + x0) * C];
        f16x8 v11 = *(const f16x8*)&p[(long)(y1 * W + x1) * C];
        f16x8 o;
#pragma unroll
        for (int j = 0; j < 8; j++) {
            float top = (float)v00[j] * (1.f - wx) + (float)v01[j] * wx;
            float bot = (float)v10[j] * (1.f - wx) + (float)v11[j] * wx;
            o[j] = (f16)(top * (1.f - wy) + bot * wy);
        }
        *(f16x8*)&out[((long)bb * OH * OW + l) * C + c8 * 8] = o;
    }
}

// Fused energy+softmax+PV (r15-proven). Wave per pixel.
template<int C, int CV, int WDIM>
__global__ __launch_bounds__(256)
void attpv_k(const f16* __restrict__ q, const f16* __restrict__ k,
             const f16* __restrict__ v, f16* __restrict__ out)
{
    const int HW = WDIM * WDIM;
    const int wave = threadIdx.x >> 6, lane = threadIdx.x & 63;
    const int l = blockIdx.x * 4 + wave;
    const int bb = blockIdx.y;
    const int y = l / WDIM, x = l % WDIM;
    int offs[9]; bool val[9];
#pragma unroll
    for (int t = 0; t < 9; t++) {
        int aa = t / 3, bj = t % 3;
        int yy = y + 2 * aa - 2, xx = x + 2 * bj - 2;
        val[t] = (yy >= 0 && yy < WDIM && xx >= 0 && xx < WDIM);
        offs[t] = val[t] ? yy * WDIM + xx : 0;
    }
    const int NC = C / 64;
    float qv[NC];
    const f16* qr = q + ((long)bb * HW + l) * C;
#pragma unroll
    for (int ch = 0; ch < NC; ch++) qv[ch] = (float)qr[lane + ch * 64];
    const f16* kb = k + (long)bb * HW * C;
    float e[9];
#pragma unroll
    for (int t = 0; t < 9; t++) {
        float s = 0.f;
        if (val[t]) {
            const f16* kr = kb + (long)offs[t] * C;
#pragma unroll
            for (int ch = 0; ch < NC; ch++)
                s = fmaf(qv[ch], (float)kr[lane + ch * 64], s);
#pragma unroll
            for (int msk = 1; msk < 64; msk <<= 1) s += __shfl_xor(s, msk);
        }
        e[t] = s;
    }
    float mx = e[0];
#pragma unroll
    for (int t = 1; t < 9; t++) mx = fmaxf(mx, e[t]);
    float ssum = 0.f; float a[9];
#pragma unroll
    for (int t = 0; t < 9; t++) { a[t] = expf(e[t] - mx); ssum += a[t]; }
    float inv = 1.f / ssum;
#pragma unroll
    for (int t = 0; t < 9; t++) a[t] *= inv;
    const f16* vb = v + (long)bb * HW * CV;
    f16* ob = out + ((long)bb * HW + l) * CV;
#pragma unroll
    for (int ch = 0; ch < CV / 128; ch++) {
        int c = lane * 2 + ch * 128;
        float s0 = 0.f, s1 = 0.f;
#pragma unroll
        for (int t = 0; t < 9; t++) {
            if (!val[t]) continue;
            f16x2 vv = *(const f16x2*)&vb[(long)offs[t] * CV + c];
            s0 = fmaf(a[t], (float)vv[0], s0);
            s1 = fmaf(a[t], (float)vv[1], s1);
        }
        f16x2 o2; o2[0] = (f16)s0; o2[1] = (f16)s1;
        *(f16x2*)&ob[c] = o2;
    }
}

// codeword squared norms — wave per codeword, shuffle reduce
__global__ void cc_k(const float* __restrict__ cw, float* __restrict__ cc, int D)
{
    int k = blockIdx.x;
    int lane = threadIdx.x;
    float s = 0.f;
    for (int d = lane; d < D; d += 64) { float v = cw[(long)k * D + d]; s += v * v; }
#pragma unroll
    for (int msk = 1; msk < 64; msk <<= 1) s += __shfl_xor(s, msk);
    if (lane == 0) cc[k] = s;
}

// soft-assign: x f16 NHWC, xc f16 [l][32] -> A f32 [l][32]
__global__ __launch_bounds__(256)
void assign_h(const f16* __restrict__ x, const f16* __restrict__ xc,
              const float* __restrict__ cc, const float* __restrict__ scale,
              float* __restrict__ A)
{
    int l = blockIdx.x * 256 + threadIdx.x;
    int bb = blockIdx.y;
    if (l >= 4096) return;
    const f16* xr = x + ((long)bb * 4096 + l) * 512;
    float xx = 0.f;
    for (int d = 0; d < 512; d += 8) {
        f16x8 v = *(const f16x8*)&xr[d];
#pragma unroll
        for (int j = 0; j < 8; j++) { float f = (float)v[j]; xx = fmaf(f, f, xx); }
    }
    const f16* xcr = xc + ((long)bb * 4096 + l) * 32;
    float e[32]; float mx = -1e30f;
#pragma unroll
    for (int k2 = 0; k2 < 32; k2++) {
        float dist = xx + cc[k2] - 2.f * (float)xcr[k2];
        float en = -scale[k2] * dist;
        e[k2] = en; mx = fmaxf(mx, en);
    }
    float s = 0.f;
#pragma unroll
    for (int k2 = 0; k2 < 32; k2++) { e[k2] = expf(e[k2] - mx); s += e[k2]; }
    float inv = 1.f / s;
    long base = ((long)bb * 4096 + l) * 32;
#pragma unroll
    for (int k2 = 0; k2 < 32; k2++) A[base + k2] = e[k2] * inv;
}

__global__ __launch_bounds__(256)
void asum_k(const float* __restrict__ A, float* __restrict__ Asum, int HW)
{
    int k2 = blockIdx.x, b = blockIdx.y;
    float s = 0.f;
    for (int l = threadIdx.x; l < HW; l += 256) s += A[((long)b * HW + l) * 32 + k2];
    __shared__ float sh[256];
    sh[threadIdx.x] = s;
    __syncthreads();
    for (int o = 128; o > 0; o >>= 1) {
        if (threadIdx.x < o) sh[threadIdx.x] += sh[threadIdx.x + o];
        __syncthreads();
    }
    if (threadIdx.x == 0) Asum[b * 32 + k2] = sh[0];
}

// Et partial GEMM: Etp[z][k2][d] = sum_{l in chunk} A[l][k2] * X[l][d]
__global__ __launch_bounds__(256)
void etg_k(const float* __restrict__ Af, const f16* __restrict__ Xh, float* __restrict__ Etp)
{
    int z = blockIdx.z; int b = z >> 4; int ch = z & 15;
    int kbase = ch * 256;
    const float* Ab = Af + (long)b * 4096 * 32;
    const f16* Xb = Xh + (long)b * 4096 * 512;
    int n0 = blockIdx.x * 64;
    __shared__ float As[16][65];
    __shared__ float Bs[16][64];
    int tid = threadIdx.x; int tx = tid & 15, ty = tid >> 4;
    float acc[4][4];
#pragma unroll
    for (int i = 0; i < 4; i++)
#pragma unroll
        for (int j = 0; j < 4; j++) acc[i][j] = 0.f;
    for (int k0 = 0; k0 < 256; k0 += 16) {
#pragma unroll
        for (int i = 0; i < 4; i++) {
            int idx = tid + i * 256;
            int kk = idx & 15, mm = idx >> 4;
            float vv = 0.f;
            if (mm < 32) vv = Ab[(long)(kbase + k0 + kk) * 32 + mm];
            As[kk][mm] = vv;
        }
#pragma unroll
        for (int i = 0; i < 4; i++) {
            int idx = tid + i * 256;
            int nn = idx & 63, kk = idx >> 6;
            Bs[kk][nn] = (float)Xb[(long)(kbase + k0 + kk) * 512 + n0 + nn];
        }
        __syncthreads();
#pragma unroll
        for (int kk = 0; kk < 16; kk++) {
            float a[4], bb2[4];
#pragma unroll
            for (int i = 0; i < 4; i++) a[i] = As[kk][ty + i * 16];
#pragma unroll
            for (int j = 0; j < 4; j++) bb2[j] = Bs[kk][tx + j * 16];
#pragma unroll
            for (int i = 0; i < 4; i++)
#pragma unroll
                for (int j = 0; j < 4; j++)
                    acc[i][j] = fmaf(a[i], bb2[j], acc[i][j]);
        }
        __syncthreads();
    }
    float* Ob = Etp + (long)z * 32 * 512;
#pragma unroll
    for (int i = 0; i < 4; i++) {
        int m = ty + i * 16;
        if (m >= 32) continue;
#pragma unroll
        for (int j = 0; j < 4; j++) Ob[(long)m * 512 + n0 + tx + j * 16] = acc[i][j];
    }
}

// E[b,k,d] = sum_chunks Etp - Asum*cw
__global__ void efix2_k(const float* __restrict__ Etp, const float* __restrict__ asumf,
                        const float* __restrict__ cwf, float* __restrict__ Ef)
{
    int i = blockIdx.x * 256 + threadIdx.x;
    if (i >= 2 * 32 * 512) return;
    int d = i % 512; int k2 = (i / 512) % 32; int bb = i / (512 * 32);
    float s = 0.f;
#pragma unroll
    for (int c2 = 0; c2 < 16; c2++) s += Etp[((long)(bb * 16 + c2) * 32 + k2) * 512 + d];
    Ef[i] = s - asumf[bb * 32 + k2] * cwf[k2 * 512 + d];
}

// BN stats (mean/var) per channel, f32 input (for E)
__global__ __launch_bounds__(256)
void bn_stats_k(const float* __restrict__ x, float* __restrict__ mv,
                int HW, int Nb, long strideN)
{
    int c = blockIdx.x;
    long total = (long)Nb * HW;
    float s = 0.f, s2 = 0.f;
    for (long i = threadIdx.x; i < total; i += 256) {
        int n = (int)(i / HW); int l = (int)(i % HW);
        float v = x[(long)n * strideN + (long)c * HW + l];
        s += v; s2 += v * v;
    }
    __shared__ float sh0[256], sh1[256];
    sh0[threadIdx.x] = s; sh1[threadIdx.x] = s2;
    __syncthreads();
    for (int o = 128; o > 0; o >>= 1) {
        if (threadIdx.x < o) { sh0[threadIdx.x] += sh0[threadIdx.x + o]; sh1[threadIdx.x] += sh1[threadIdx.x + o]; }
        __syncthreads();
    }
    if (threadIdx.x == 0) {
        float inv = 1.f / (float)total;
        float m = sh0[0] * inv;
        mv[2 * c] = m;
        mv[2 * c + 1] = sh1[0] * inv - m * m;
    }
}

// en[b,d] = mean_k relu(BN1d(E[b,k,d]))
__global__ __launch_bounds__(256)
void en_k(const float* __restrict__ E, const float* __restrict__ mv,
          const float* __restrict__ gK, const float* __restrict__ bK,
          float* __restrict__ en, int D)
{
    int i = blockIdx.x * 256 + threadIdx.x;
    if (i >= 2 * D) return;
    int b = i / D, d = i % D;
    float s = 0.f;
#pragma unroll
    for (int k2 = 0; k2 < 32; k2++) {
        float m = mv[2 * k2], vv = mv[2 * k2 + 1];
        float r = (E[((long)b * 32 + k2) * D + d] - m) * rsqrtf(vv + EPSBN) * gK[k2] + bK[k2];
        s += fmaxf(r, 0.f);
    }
    en[i] = s * (1.f / 32.f);
}

__global__ __launch_bounds__(256)
void fc_k(const float* __restrict__ W, const float* __restrict__ bias,
          const float* __restrict__ in, float* __restrict__ out,
          int O, int D, int mode)
{
    int o = blockIdx.x * 256 + threadIdx.x;
    int b = blockIdx.y;
    if (o >= O) return;
    const float* ib = in + (long)b * D;
    float s = bias[o];
    for (int d = 0; d < D; d++) s += W[(long)o * D + d] * ib[d];
    if (mode == 1) s = 1.f / (1.f + expf(-s));
    out[(long)b * O + o] = s;
}

// y = relu(feat * (1+gamma)), f16 NHWC, 8/thread
__global__ __launch_bounds__(256)
void ymul_h(const f16* __restrict__ feat, const float* __restrict__ gamma,
            f16* __restrict__ y)
{
    long i8 = (blockIdx.x * 256L + threadIdx.x) * 8;
    if (i8 >= 2L * 4096 * 512) return;
    int c0 = (int)(i8 % 512);
    int bb = (int)(i8 / (4096L * 512));
    f16x8 v = *(const f16x8*)&feat[i8];
    f16x8 o;
#pragma unroll
    for (int j = 0; j < 8; j++)
        o[j] = (f16)fmaxf((float)v[j] * (1.f + gamma[bb * 512 + c0 + j]), 0.f);
    *(f16x8*)&y[i8] = o;
}

static inline dim3 hgrid(int M, int N) { return dim3((N + 127) / 128, (M + 63) / 64, 2); }

extern "C" void kernel_launch(void* const* d_in, const int* in_sizes, int n_in,
                              void* d_out, int out_size, void* d_ws, size_t ws_size,
                              hipStream_t stream)
{
    (void)in_sizes; (void)n_in; (void)out_size; (void)ws_size;
    const float* c2  = (const float*)d_in[1];
    const float* c3  = (const float*)d_in[2];
    const float* c4  = (const float*)d_in[3];
    const float* wq4 = (const float*)d_in[7];
    const float* gq4 = (const float*)d_in[8];
    const float* bq4 = (const float*)d_in[9];
    const float* wk4 = (const float*)d_in[10];
    const float* gk4 = (const float*)d_in[11];
    const float* bk4 = (const float*)d_in[12];
    const float* wv4 = (const float*)d_in[13];
    const float* wq3 = (const float*)d_in[14];
    const float* gq3 = (const float*)d_in[15];
    const float* bq3 = (const float*)d_in[16];
    const float* wk3 = (const float*)d_in[17];
    const float* gk3 = (const float*)d_in[18];
    const float* bk3 = (const float*)d_in[19];
    const float* wv3 = (const float*)d_in[20];
    const float* w5  = (const float*)d_in[21];
    const float* g5  = (const float*)d_in[22];
    const float* b5  = (const float*)d_in[23];
    const float* we  = (const float*)d_in[24];
    const float* ge  = (const float*)d_in[25];
    const float* be  = (const float*)d_in[26];
    const float* cw  = (const float*)d_in[27];
    const float* scl = (const float*)d_in[28];
    const float* gK  = (const float*)d_in[29];
    const float* bK  = (const float*)d_in[30];
    const float* wfc = (const float*)d_in[31];
    const float* bfc = (const float*)d_in[32];
    const float* wse = (const float*)d_in[33];
    const float* bse = (const float*)d_in[34];
    const float* w6  = (const float*)d_in[35];
    const float* b6  = (const float*)d_in[36];
    float* outp = (float*)d_out;
    char* ws = (char*)d_ws;

    // ---- workspace (byte offsets), liveness-checked overlays ----
    auto H = [&](long off) { return (f16*)(ws + off); };
    auto F = [&](long off) { return (float*)(ws + off); };
    const long O_wq4h = 0;
    const long O_wk4h = 262144;
    const long O_wv4h = 786432;
    const long O_wq3h = 4980736;
    const long O_wk3h = 5046272;
    const long O_wv3h = 5177344;
    const long O_w5r  = 6225920;
    const long O_weh  = 10944512;
    const long O_cwh  = 11468800;
    const long O_w6h  = 11501568;
    const long O_c3h  = 11665408;
    const long O_Xh   = 11665408;
    const long O_c4h  = 20054016;
    const long O_cku4h= 22151168;
    const long O_v3h  = 22151168;
    const long O_q4h  = 30539776;
    const long O_k4h  = 31064064;
    const long O_v4h  = 31588352;
    const long O_xch  = 30834688;
    const long O_Af   = 31358976;
    const long O_Etp  = 32407552;
    const long O_Ef   = 34504704;
    const long O_asum = 34635776;
    const long O_cc   = 34636032;
    const long O_en   = 34636160;
    const long O_gam  = 34640256;
    const long O_mv   = 34644352;
    const long O_out4h= 35856384;
    const long O_yh   = 35856384;
    const long O_c2h  = 40050688;
    const long O_cku3h= 48439296;
    const long O_feath= 48439296;
    const long O_out3h= 56827904;
    const long O_q3h  = 65216512;
    const long O_k3h  = 66265088;

    float* mv = F(O_mv);

    // ---- conversions ----
    chw2nhwc_k<<<dim3(128, 16, 2), 256, 0, stream>>>(c2, H(O_c2h), 512, 4096);
    chw2nhwc_k<<<dim3(32, 32, 2), 256, 0, stream>>>(c3, H(O_c3h), 1024, 1024);
    chw2nhwc_k<<<dim3(8, 64, 2), 256, 0, stream>>>(c4, H(O_c4h), 2048, 256);
    auto cvt = [&](const float* s, long o, long n) {
        f2h_k<<<(int)((n + 255) / 256), 256, 0, stream>>>(s, H(o), n);
    };
    cvt(wq4, O_wq4h, 128L * 1024); cvt(wk4, O_wk4h, 128L * 2048);
    cvt(wv4, O_wv4h, 1024L * 2048); cvt(wq3, O_wq3h, 64L * 512);
    cvt(wk3, O_wk3h, 64L * 1024); cvt(wv3, O_wv3h, 512L * 1024);
    cvt(we, O_weh, 512L * 512); cvt(cw, O_cwh, 32L * 512);
    cvt(w6, O_w6h, 150L * 512);
    w5r_k<<<9216, 256, 0, stream>>>(w5, H(O_w5r));
    zero_k<<<11, 256, 0, stream>>>(mv, 2816);

    // ---- Stage A: local_up(c3, c4) -> out4h (NHWC 2x1024x1024) ----
    hgemm_k<0><<<hgrid(128, 1024), 256, 0, stream>>>(H(O_wq4h), H(O_c3h), H(O_q4h), nullptr,
        128, 1024, 1024, 1024, 1024L * 1024, 1024L * 128, 0, 0, mv + 0);
    bnapply_k<<<128, 256, 0, stream>>>(H(O_q4h), mv + 0, gq4, bq4, 128, 2L * 1024 * 128, 1.f / 2048.f, 0);
    upsample_h8<<<2048, 256, 0, stream>>>(H(O_c4h), H(O_cku4h), 256, 16, 16, 32, 32);
    hgemm_k<0><<<hgrid(128, 1024), 256, 0, stream>>>(H(O_wk4h), H(O_cku4h), H(O_k4h), nullptr,
        128, 2048, 1024, 2048, 1024L * 2048, 1024L * 128, 0, 0, mv + 256);
    bnapply_k<<<128, 256, 0, stream>>>(H(O_k4h), mv + 256, gk4, bk4, 128, 2L * 1024 * 128, 1.f / 2048.f, 0);
    hgemm_k<0><<<hgrid(1024, 1024), 256, 0, stream>>>(H(O_wv4h), H(O_cku4h), H(O_v4h), nullptr,
        1024, 2048, 1024, 2048, 1024L * 2048, 1024L * 1024, 0, 0, nullptr);
    attpv_k<128, 1024, 32><<<dim3(256, 2), 256, 0, stream>>>(
        H(O_q4h), H(O_k4h), H(O_v4h), H(O_out4h));

    // ---- Stage B: local_up(c2, out4) -> out3h (NHWC 2x4096x512) ----
    hgemm_k<0><<<hgrid(64, 4096), 256, 0, stream>>>(H(O_wq3h), H(O_c2h), H(O_q3h), nullptr,
        64, 512, 4096, 512, 4096L * 512, 4096L * 64, 0, 0, mv + 512);
    bnapply_k<<<256, 256, 0, stream>>>(H(O_q3h), mv + 512, gq3, bq3, 64, 2L * 4096 * 64, 1.f / 8192.f, 0);
    upsample_h8<<<4096, 256, 0, stream>>>(H(O_out4h), H(O_cku3h), 128, 32, 32, 64, 64);
    hgemm_k<0><<<hgrid(64, 4096), 256, 0, stream>>>(H(O_wk3h), H(O_cku3h), H(O_k3h), nullptr,
        64, 1024, 4096, 1024, 4096L * 1024, 4096L * 64, 0, 0, mv + 640);
    bnapply_k<<<256, 256, 0, stream>>>(H(O_k3h), mv + 640, gk3, bk3, 64, 2L * 4096 * 64, 1.f / 8192.f, 0);
    hgemm_k<0><<<hgrid(512, 4096), 256, 0, stream>>>(H(O_wv3h), H(O_cku3h), H(O_v3h), nullptr,
        512, 1024, 4096, 1024, 4096L * 1024, 4096L * 512, 0, 0, nullptr);
    attpv_k<64, 512, 64><<<dim3(1024, 2), 256, 0, stream>>>(
        H(O_q3h), H(O_k3h), H(O_v3h), H(O_out3h));

    // ---- Stage C: feat = relu(BN(conv3x3(out3))) ----
    hgemm_k<1><<<hgrid(512, 4096), 256, 0, stream>>>(H(O_w5r), H(O_out3h), H(O_feath), nullptr,
        512, 4608, 4096, 512, 4096L * 512, 4096L * 512, 64, 64, mv + 768);
    bnapply_k<<<2048, 256, 0, stream>>>(H(O_feath), mv + 768, g5, b5, 512, 2L * 4096 * 512, 1.f / 8192.f, 1);

    // ---- Stage D: enc_module ----
    hgemm_k<0><<<hgrid(512, 4096), 256, 0, stream>>>(H(O_weh), H(O_feath), H(O_Xh), nullptr,
        512, 512, 4096, 512, 4096L * 512, 4096L * 512, 0, 0, mv + 1792);
    bnapply_k<<<2048, 256, 0, stream>>>(H(O_Xh), mv + 1792, ge, be, 512, 2L * 4096 * 512, 1.f / 8192.f, 1);
    hgemm_k<0><<<hgrid(32, 4096), 256, 0, stream>>>(H(O_cwh), H(O_Xh), H(O_xch), nullptr,
        32, 512, 4096, 512, 4096L * 512, 4096L * 32, 0, 0, nullptr);
    cc_k<<<32, 64, 0, stream>>>(cw, F(O_cc), 512);
    assign_h<<<dim3(16, 2), 256, 0, stream>>>(H(O_Xh), H(O_xch), F(O_cc), scl, F(O_Af));
    asum_k<<<dim3(32, 2), 256, 0, stream>>>(F(O_Af), F(O_asum), 4096);
    etg_k<<<dim3(8, 1, 32), 256, 0, stream>>>(F(O_Af), H(O_Xh), F(O_Etp));
    efix2_k<<<128, 256, 0, stream>>>(F(O_Etp), F(O_asum), cw, F(O_Ef));
    bn_stats_k<<<32, 256, 0, stream>>>(F(O_Ef), mv + 2816, 512, 2, 32L * 512);
    en_k<<<4, 256, 0, stream>>>(F(O_Ef), mv + 2816, gK, bK, F(O_en), 512);
    fc_k<<<dim3(2, 2), 256, 0, stream>>>(wfc, bfc, F(O_en), F(O_gam), 512, 512, 1);
    fc_k<<<dim3(1, 2), 256, 0, stream>>>(wse, bse, F(O_en), outp + 1228800, 150, 512, 0);
    ymul_h<<<2048, 256, 0, stream>>>(H(O_feath), F(O_gam), H(O_yh));

    // ---- Stage E: seg = w6 @ y + b6 -> d_out (CHW f32) ----
    hgemm_k<2><<<hgrid(150, 4096), 256, 0, stream>>>(H(O_w6h), H(O_yh), outp, b6,
        150, 512, 4096, 512, 4096L * 512, 150L * 4096, 0, 0, nullptr);
}

// Round 17
// 573.706 us; speedup vs baseline: 1.2156x; 1.2156x over previous
//
#include <hip/hip_runtime.h>
#include <math.h>

#define EPSBN 1e-5f

typedef _Float16 f16;
typedef _Float16 f16x8 __attribute__((ext_vector_type(8)));
typedef _Float16 f16x4 __attribute__((ext_vector_type(4)));
typedef _Float16 f16x2 __attribute__((ext_vector_type(2)));
typedef float f32x4 __attribute__((ext_vector_type(4)));

static __device__ inline f16x8 h8zero() {
    f16x8 v;
#pragma unroll
    for (int j = 0; j < 8; j++) v[j] = (f16)0.f;
    return v;
}

// ---------------------------------------------------------------------------
// MFMA f16 GEMM (r11-proven, byte-identical). BM=64, BN=128, BK=64.
// 2-DEEP register pipeline, pre-swizzled source + linear LDS write + swizzled
// read. Optional fused BN column sums via shfl+atomicAdd.
// MODE 0: out f16 NHWC; MODE 1: conv3x3-d1 (spatial hardcoded 64x64);
// MODE 2: out f32 CHW + bias.
// ---------------------------------------------------------------------------
template<int MODE>
__global__ __launch_bounds__(256)
void hgemm_k(const f16* __restrict__ Wh, const f16* __restrict__ act,
             void* __restrict__ outv, const float* __restrict__ bias,
             int M, int K, int N, int Cact, long actStride, long outStride,
             int IW, int IH, float* __restrict__ sums)
{
    const int b = blockIdx.z;
    const int n0 = blockIdx.x * 128, m0 = blockIdx.y * 64;
    const f16* actb = act + (long)b * actStride;
    __shared__ __align__(16) f16 As[2][64 * 64];
    __shared__ __align__(16) f16 Bs[2][128 * 64];
    const int tid = threadIdx.x;
    const int wave = tid >> 6, lane = tid & 63;
    const int wm = (wave >> 1) * 32, wn = (wave & 1) * 64;
    const int lr = lane & 15, lg = lane >> 4;
    f32x4 acc[2][4];
#pragma unroll
    for (int i = 0; i < 2; i++)
#pragma unroll
        for (int j = 0; j < 4; j++)
#pragma unroll
            for (int r = 0; r < 4; r++) acc[i][j][r] = 0.f;

    const int nt = K >> 6;           // EVEN for all shapes used
    f16x8 raA[2], rbA[4], raB[2], rbB[4];

    auto LOADA = [&](int t) {
        const int kt = t << 6;
#pragma unroll
        for (int u = 0; u < 2; u++) {
            int idx = u * 256 + tid;
            int row = idx >> 3, slot = idx & 7;
            int col = kt + ((slot ^ (row & 7)) << 3);
            int m = m0 + row;
            raA[u] = (m < M) ? *(const f16x8*)&Wh[(long)m * K + col] : h8zero();
        }
#pragma unroll
        for (int u = 0; u < 4; u++) {
            int idx = u * 256 + tid;
            int row = idx >> 3, slot = idx & 7;
            int scol = (slot ^ (row & 7)) << 3;
            int n = n0 + row;
            if (MODE == 1) {
                int tap = kt >> 9;
                int kc = (kt & 511) + scol;
                int dy = tap / 3 - 1, dx = tap % 3 - 1;
                int yy = (n >> 6) + dy, xx = (n & 63) + dx;   // 64x64 spatial
                rbA[u] = (yy >= 0 && yy < 64 && xx >= 0 && xx < 64)
                        ? *(const f16x8*)&actb[(long)((yy << 6) + xx) * Cact + kc]
                        : h8zero();
            } else {
                rbA[u] = *(const f16x8*)&actb[(long)n * Cact + kt + scol];
            }
        }
    };
    auto LOADB = [&](int t) {
        const int kt = t << 6;
#pragma unroll
        for (int u = 0; u < 2; u++) {
            int idx = u * 256 + tid;
            int row = idx >> 3, slot = idx & 7;
            int col = kt + ((slot ^ (row & 7)) << 3);
            int m = m0 + row;
            raB[u] = (m < M) ? *(const f16x8*)&Wh[(long)m * K + col] : h8zero();
        }
#pragma unroll
        for (int u = 0; u < 4; u++) {
            int idx = u * 256 + tid;
            int row = idx >> 3, slot = idx & 7;
            int scol = (slot ^ (row & 7)) << 3;
            int n = n0 + row;
            if (MODE == 1) {
                int tap = kt >> 9;
                int kc = (kt & 511) + scol;
                int dy = tap / 3 - 1, dx = tap % 3 - 1;
                int yy = (n >> 6) + dy, xx = (n & 63) + dx;
                rbB[u] = (yy >= 0 && yy < 64 && xx >= 0 && xx < 64)
                        ? *(const f16x8*)&actb[(long)((yy << 6) + xx) * Cact + kc]
                        : h8zero();
            } else {
                rbB[u] = *(const f16x8*)&actb[(long)n * Cact + kt + scol];
            }
        }
    };
    auto WRITEA = [&](int bufw) {
#pragma unroll
        for (int u = 0; u < 2; u++) {
            int idx = u * 256 + tid;
            int row = idx >> 3, slot = idx & 7;
            *(f16x8*)&As[bufw][(row * 8 + slot) * 8] = raA[u];
        }
#pragma unroll
        for (int u = 0; u < 4; u++) {
            int idx = u * 256 + tid;
            int row = idx >> 3, slot = idx & 7;
            *(f16x8*)&Bs[bufw][(row * 8 + slot) * 8] = rbA[u];
        }
    };
    auto WRITEB = [&](int bufw) {
#pragma unroll
        for (int u = 0; u < 2; u++) {
            int idx = u * 256 + tid;
            int row = idx >> 3, slot = idx & 7;
            *(f16x8*)&As[bufw][(row * 8 + slot) * 8] = raB[u];
        }
#pragma unroll
        for (int u = 0; u < 4; u++) {
            int idx = u * 256 + tid;
            int row = idx >> 3, slot = idx & 7;
            *(f16x8*)&Bs[bufw][(row * 8 + slot) * 8] = rbB[u];
        }
    };
    auto MFMA = [&](int bufr) {
#pragma unroll
        for (int s = 0; s < 2; s++) {
            f16x8 af[2], bf[4];
#pragma unroll
            for (int i = 0; i < 2; i++) {
                int r = wm + i * 16 + lr;
                af[i] = *(const f16x8*)&As[bufr][(r * 8 + ((s * 4 + lg) ^ (r & 7))) * 8];
            }
#pragma unroll
            for (int j = 0; j < 4; j++) {
                int r = wn + j * 16 + lr;
                bf[j] = *(const f16x8*)&Bs[bufr][(r * 8 + ((s * 4 + lg) ^ (r & 7))) * 8];
            }
#pragma unroll
            for (int i = 0; i < 2; i++)
#pragma unroll
                for (int j = 0; j < 4; j++)
                    acc[i][j] = __builtin_amdgcn_mfma_f32_16x16x32_f16(af[i], bf[j], acc[i][j], 0, 0, 0);
        }
    };

    LOADA(0); WRITEA(0); LOADB(1);
    __syncthreads();
    int buf = 0;
    for (int t = 0; t < nt; t += 2) {
        if (t + 2 < nt) LOADA(t + 2);
        MFMA(buf);
        WRITEB(buf ^ 1);
        __syncthreads();
        buf ^= 1;
        if (t + 3 < nt) LOADB(t + 3);
        MFMA(buf);
        if (t + 2 < nt) WRITEA(buf ^ 1);
        __syncthreads();
        buf ^= 1;
    }

    if (MODE == 2) {
        float* outp = (float*)outv + (long)b * outStride;
#pragma unroll
        for (int i = 0; i < 2; i++)
#pragma unroll
            for (int j = 0; j < 4; j++) {
                int n = n0 + wn + j * 16 + lr;
#pragma unroll
                for (int r = 0; r < 4; r++) {
                    int m = m0 + wm + i * 16 + lg * 4 + r;
                    if (m < M) outp[(long)m * N + n] = acc[i][j][r] + bias[m];
                }
            }
    } else {
        f16* outp = (f16*)outv + (long)b * outStride;
#pragma unroll
        for (int i = 0; i < 2; i++)
#pragma unroll
            for (int j = 0; j < 4; j++) {
                int n = n0 + wn + j * 16 + lr;
                int mb = m0 + wm + i * 16 + lg * 4;
                if (mb < M) {
                    f16x4 hv;
#pragma unroll
                    for (int r = 0; r < 4; r++) hv[r] = (f16)acc[i][j][r];
                    *(f16x4*)&outp[(long)n * M + mb] = hv;
                }
            }
        if (sums) {
#pragma unroll
            for (int i = 0; i < 2; i++)
#pragma unroll
                for (int r = 0; r < 4; r++) {
                    int m = m0 + wm + i * 16 + lg * 4 + r;
                    float s = 0.f, s2 = 0.f;
#pragma unroll
                    for (int j = 0; j < 4; j++) {
                        float v = (float)(f16)acc[i][j][r];   // rounded value
                        s += v; s2 += v * v;
                    }
#pragma unroll
                    for (int msk = 1; msk < 16; msk <<= 1) {
                        s += __shfl_xor(s, msk);
                        s2 += __shfl_xor(s2, msk);
                    }
                    if (lr == 0 && m < M) {
                        atomicAdd(&sums[2 * m], s);
                        atomicAdd(&sums[2 * m + 1], s2);
                    }
                }
        }
    }
}

// CHW f32 -> NHWC f16 tiled transpose (C, HW multiples of 32)
__global__ __launch_bounds__(256)
void chw2nhwc_k(const float* __restrict__ in, f16* __restrict__ out, int C, int HW)
{
    int b = blockIdx.z;
    int l0 = blockIdx.x * 32, c0 = blockIdx.y * 32;
    __shared__ float t[32][33];
    int tx = threadIdx.x & 31, ty = threadIdx.x >> 5;
    const float* ib = in + (long)b * C * HW;
#pragma unroll
    for (int j = 0; j < 4; j++) {
        int c = c0 + ty + j * 8;
        t[ty + j * 8][tx] = ib[(long)c * HW + l0 + tx];
    }
    __syncthreads();
    f16* ob = out + (long)b * HW * C;
#pragma unroll
    for (int j = 0; j < 4; j++) {
        int l = l0 + ty + j * 8;
        ob[(long)l * C + c0 + tx] = (f16)t[tx][ty + j * 8];
    }
}

// flat f32 -> f16
__global__ void f2h_k(const float* __restrict__ src, f16* __restrict__ dst, long n)
{
    long i = blockIdx.x * 256L + threadIdx.x;
    if (i < n) dst[i] = (f16)src[i];
}

// w5 (O,C,3,3) f32 -> w5r[O][tap][C] f16  (K ordered taps-outer, c-inner)
__global__ void w5r_k(const float* __restrict__ src, f16* __restrict__ dst)
{
    long i = blockIdx.x * 256L + threadIdx.x;
    if (i >= 9L * 512 * 512) return;
    int c = (int)(i % 512); long t2 = i / 512;
    int t = (int)(t2 % 9); int o = (int)(t2 / 9);
    dst[i] = (f16)src[(long)o * 4608 + c * 9 + t];
}

__global__ void zero_k(float* __restrict__ p, int n)
{
    int i = blockIdx.x * 256 + threadIdx.x;
    if (i < n) p[i] = 0.f;
}

// apply BN (from raw sums) elementwise, f16 in/out, 8 elems/thread
__global__ __launch_bounds__(256)
void bnapply_k(f16* __restrict__ x, const float* __restrict__ mv,
               const float* __restrict__ g, const float* __restrict__ bta,
               int C, long total, float inv, int dorelu)
{
    long i8 = (blockIdx.x * 256L + threadIdx.x) * 8;
    if (i8 >= total) return;
    int c0 = (int)(i8 % C);
    f16x8 v = *(f16x8*)&x[i8];
#pragma unroll
    for (int j = 0; j < 8; j++) {
        int c = c0 + j;
        float m = mv[2 * c] * inv;
        float var = mv[2 * c + 1] * inv - m * m;
        float r = ((float)v[j] - m) * rsqrtf(var + EPSBN) * g[c] + bta[c];
        if (dorelu) r = fmaxf(r, 0.f);
        v[j] = (f16)r;
    }
    *(f16x8*)&x[i8] = v;
}

// bilinear upsample align_corners=True, NHWC f16, 8 channels/thread
__global__ __launch_bounds__(256)
void upsample_h8(const f16* __restrict__ in, f16* __restrict__ out,
                 int C8, int H, int W, int OH, int OW)
{
    long total = 2L * C8 * OH * OW;
    float ry = (float)(H - 1) / (float)(OH - 1);
    float rx = (float)(W - 1) / (float)(OW - 1);
    int C = C8 * 8;
    for (long i = blockIdx.x * 256L + threadIdx.x; i < total; i += (long)gridDim.x * 256) {
        int c8 = (int)(i % C8); long t = i / C8;
        int l = (int)(t % (OH * OW)); int bb = (int)(t / (OH * OW));
        int oy = l / OW, ox = l % OW;
        float fy = oy * ry, fx = ox * rx;
        int y0 = (int)fy, x0 = (int)fx;
        int y1 = min(y0 + 1, H - 1), x1 = min(x0 + 1, W - 1);
        float wy = fy - y0, wx = fx - x0;
        const f16* p = in + (long)bb * H * W * C + c8 * 8;
        f16x8 v00 = *(const f16x8*)&p[(long)(y0 * W + x0) * C];
        f16x8 v01 = *(const f16x8*)&p[(long)(y0 * W + x1) * C];
        f16x8 v10 = *(const f16x8*)&p[(long)(y1 * W + x0) * C];
        f16x8 v11 = *(const f16x8*)&p[(long)(y1 * W + x1) * C];
        f16x8 o;
#pragma unroll
        for (int j = 0; j < 8; j++) {
            float top = (float)v00[j] * (1.f - wx) + (float)v01[j] * wx;
            float bot = (float)v10[j] * (1.f - wx) + (float)v11[j] * wx;
            o[j] = (f16)(top * (1.f - wy) + bot * wy);
        }
        *(f16x8*)&out[((long)bb * OH * OW + l) * C + c8 * 8] = o;
    }
}

// Fused energy+softmax+PV (r15-proven). Wave per pixel.
template<int C, int CV, int WDIM>
__global__ __launch_bounds__(256)
void attpv_k(const f16* __restrict__ q, const f16* __restrict__ k,
             const f16* __restrict__ v, f16* __restrict__ out)
{
    const int HW = WDIM * WDIM;
    const int wave = threadIdx.x >> 6, lane = threadIdx.x & 63;
    const int l = blockIdx.x * 4 + wave;
    const int bb = blockIdx.y;
    const int y = l / WDIM, x = l % WDIM;
    int offs[9]; bool val[9];
#pragma unroll
    for (int t = 0; t < 9; t++) {
        int aa = t / 3, bj = t % 3;
        int yy = y + 2 * aa - 2, xx = x + 2 * bj - 2;
        val[t] = (yy >= 0 && yy < WDIM && xx >= 0 && xx < WDIM);
        offs[t] = val[t] ? yy * WDIM + xx : 0;
    }
    const int NC = C / 64;
    float qv[NC];
    const f16* qr = q + ((long)bb * HW + l) * C;
#pragma unroll
    for (int ch = 0; ch < NC; ch++) qv[ch] = (float)qr[lane + ch * 64];
    const f16* kb = k + (long)bb * HW * C;
    float e[9];
#pragma unroll
    for (int t = 0; t < 9; t++) {
        float s = 0.f;
        if (val[t]) {
            const f16* kr = kb + (long)offs[t] * C;
#pragma unroll
            for (int ch = 0; ch < NC; ch++)
                s = fmaf(qv[ch], (float)kr[lane + ch * 64], s);
#pragma unroll
            for (int msk = 1; msk < 64; msk <<= 1) s += __shfl_xor(s, msk);
        }
        e[t] = s;
    }
    float mx = e[0];
#pragma unroll
    for (int t = 1; t < 9; t++) mx = fmaxf(mx, e[t]);
    float ssum = 0.f; float a[9];
#pragma unroll
    for (int t = 0; t < 9; t++) { a[t] = expf(e[t] - mx); ssum += a[t]; }
    float inv = 1.f / ssum;
#pragma unroll
    for (int t = 0; t < 9; t++) a[t] *= inv;
    const f16* vb = v + (long)bb * HW * CV;
    f16* ob = out + ((long)bb * HW + l) * CV;
#pragma unroll
    for (int ch = 0; ch < CV / 128; ch++) {
        int c = lane * 2 + ch * 128;
        float s0 = 0.f, s1 = 0.f;
#pragma unroll
        for (int t = 0; t < 9; t++) {
            if (!val[t]) continue;
            f16x2 vv = *(const f16x2*)&vb[(long)offs[t] * CV + c];
            s0 = fmaf(a[t], (float)vv[0], s0);
            s1 = fmaf(a[t], (float)vv[1], s1);
        }
        f16x2 o2; o2[0] = (f16)s0; o2[1] = (f16)s1;
        *(f16x2*)&ob[c] = o2;
    }
}

// codeword squared norms — wave per codeword, shuffle reduce
__global__ void cc_k(const float* __restrict__ cw, float* __restrict__ cc, int D)
{
    int k = blockIdx.x;
    int lane = threadIdx.x;
    float s = 0.f;
    for (int d = lane; d < D; d += 64) { float v = cw[(long)k * D + d]; s += v * v; }
#pragma unroll
    for (int msk = 1; msk < 64; msk <<= 1) s += __shfl_xor(s, msk);
    if (lane == 0) cc[k] = s;
}

// soft-assign: x f16 NHWC, xc f16 [l][32] -> A f32 [l][32]
__global__ __launch_bounds__(256)
void assign_h(const f16* __restrict__ x, const f16* __restrict__ xc,
              const float* __restrict__ cc, const float* __restrict__ scale,
              float* __restrict__ A)
{
    int l = blockIdx.x * 256 + threadIdx.x;
    int bb = blockIdx.y;
    if (l >= 4096) return;
    const f16* xr = x + ((long)bb * 4096 + l) * 512;
    float xx = 0.f;
    for (int d = 0; d < 512; d += 8) {
        f16x8 v = *(const f16x8*)&xr[d];
#pragma unroll
        for (int j = 0; j < 8; j++) { float f = (float)v[j]; xx = fmaf(f, f, xx); }
    }
    const f16* xcr = xc + ((long)bb * 4096 + l) * 32;
    float e[32]; float mx = -1e30f;
#pragma unroll
    for (int k2 = 0; k2 < 32; k2++) {
        float dist = xx + cc[k2] - 2.f * (float)xcr[k2];
        float en = -scale[k2] * dist;
        e[k2] = en; mx = fmaxf(mx, en);
    }
    float s = 0.f;
#pragma unroll
    for (int k2 = 0; k2 < 32; k2++) { e[k2] = expf(e[k2] - mx); s += e[k2]; }
    float inv = 1.f / s;
    long base = ((long)bb * 4096 + l) * 32;
#pragma unroll
    for (int k2 = 0; k2 < 32; k2++) A[base + k2] = e[k2] * inv;
}

__global__ __launch_bounds__(256)
void asum_k(const float* __restrict__ A, float* __restrict__ Asum, int HW)
{
    int k2 = blockIdx.x, b = blockIdx.y;
    float s = 0.f;
    for (int l = threadIdx.x; l < HW; l += 256) s += A[((long)b * HW + l) * 32 + k2];
    __shared__ float sh[256];
    sh[threadIdx.x] = s;
    __syncthreads();
    for (int o = 128; o > 0; o >>= 1) {
        if (threadIdx.x < o) sh[threadIdx.x] += sh[threadIdx.x + o];
        __syncthreads();
    }
    if (threadIdx.x == 0) Asum[b * 32 + k2] = sh[0];
}

// Et partial GEMM: Etp[z][k2][d] = sum_{l in chunk} A[l][k2] * X[l][d]
__global__ __launch_bounds__(256)
void etg_k(const float* __restrict__ Af, const f16* __restrict__ Xh, float* __restrict__ Etp)
{
    int z = blockIdx.z; int b = z >> 4; int ch = z & 15;
    int kbase = ch * 256;
    const float* Ab = Af + (long)b * 4096 * 32;
    const f16* Xb = Xh + (long)b * 4096 * 512;
    int n0 = blockIdx.x * 64;
    __shared__ float As[16][65];
    __shared__ float Bs[16][64];
    int tid = threadIdx.x; int tx = tid & 15, ty = tid >> 4;
    float acc[4][4];
#pragma unroll
    for (int i = 0; i < 4; i++)
#pragma unroll
        for (int j = 0; j < 4; j++) acc[i][j] = 0.f;
    for (int k0 = 0; k0 < 256; k0 += 16) {
#pragma unroll
        for (int i = 0; i < 4; i++) {
            int idx = tid + i * 256;
            int kk = idx & 15, mm = idx >> 4;
            float vv = 0.f;
            if (mm < 32) vv = Ab[(long)(kbase + k0 + kk) * 32 + mm];
            As[kk][mm] = vv;
        }
#pragma unroll
        for (int i = 0; i < 4; i++) {
            int idx = tid + i * 256;
            int nn = idx & 63, kk = idx >> 6;
            Bs[kk][nn] = (float)Xb[(long)(kbase + k0 + kk) * 512 + n0 + nn];
        }
        __syncthreads();
#pragma unroll
        for (int kk = 0; kk < 16; kk++) {
            float a[4], bb2[4];
#pragma unroll
            for (int i = 0; i < 4; i++) a[i] = As[kk][ty + i * 16];
#pragma unroll
            for (int j = 0; j < 4; j++) bb2[j] = Bs[kk][tx + j * 16];
#pragma unroll
            for (int i = 0; i < 4; i++)
#pragma unroll
                for (int j = 0; j < 4; j++)
                    acc[i][j] = fmaf(a[i], bb2[j], acc[i][j]);
        }
        __syncthreads();
    }
    float* Ob = Etp + (long)z * 32 * 512;
#pragma unroll
    for (int i = 0; i < 4; i++) {
        int m = ty + i * 16;
        if (m >= 32) continue;
#pragma unroll
        for (int j = 0; j < 4; j++) Ob[(long)m * 512 + n0 + tx + j * 16] = acc[i][j];
    }
}

// E[b,k,d] = sum_chunks Etp - Asum*cw
__global__ void efix2_k(const float* __restrict__ Etp, const float* __restrict__ asumf,
                        const float* __restrict__ cwf, float* __restrict__ Ef)
{
    int i = blockIdx.x * 256 + threadIdx.x;
    if (i >= 2 * 32 * 512) return;
    int d = i % 512; int k2 = (i / 512) % 32; int bb = i / (512 * 32);
    float s = 0.f;
#pragma unroll
    for (int c2 = 0; c2 < 16; c2++) s += Etp[((long)(bb * 16 + c2) * 32 + k2) * 512 + d];
    Ef[i] = s - asumf[bb * 32 + k2] * cwf[k2 * 512 + d];
}

// BN stats (mean/var) per channel, f32 input (for E)
__global__ __launch_bounds__(256)
void bn_stats_k(const float* __restrict__ x, float* __restrict__ mv,
                int HW, int Nb, long strideN)
{
    int c = blockIdx.x;
    long total = (long)Nb * HW;
    float s = 0.f, s2 = 0.f;
    for (long i = threadIdx.x; i < total; i += 256) {
        int n = (int)(i / HW); int l = (int)(i % HW);
        float v = x[(long)n * strideN + (long)c * HW + l];
        s += v; s2 += v * v;
    }
    __shared__ float sh0[256], sh1[256];
    sh0[threadIdx.x] = s; sh1[threadIdx.x] = s2;
    __syncthreads();
    for (int o = 128; o > 0; o >>= 1) {
        if (threadIdx.x < o) { sh0[threadIdx.x] += sh0[threadIdx.x + o]; sh1[threadIdx.x] += sh1[threadIdx.x + o]; }
        __syncthreads();
    }
    if (threadIdx.x == 0) {
        float inv = 1.f / (float)total;
        float m = sh0[0] * inv;
        mv[2 * c] = m;
        mv[2 * c + 1] = sh1[0] * inv - m * m;
    }
}

// en[b,d] = mean_k relu(BN1d(E[b,k,d]))
__global__ __launch_bounds__(256)
void en_k(const float* __restrict__ E, const float* __restrict__ mv,
          const float* __restrict__ gK, const float* __restrict__ bK,
          float* __restrict__ en, int D)
{
    int i = blockIdx.x * 256 + threadIdx.x;
    if (i >= 2 * D) return;
    int b = i / D, d = i % D;
    float s = 0.f;
#pragma unroll
    for (int k2 = 0; k2 < 32; k2++) {
        float m = mv[2 * k2], vv = mv[2 * k2 + 1];
        float r = (E[((long)b * 32 + k2) * D + d] - m) * rsqrtf(vv + EPSBN) * gK[k2] + bK[k2];
        s += fmaxf(r, 0.f);
    }
    en[i] = s * (1.f / 32.f);
}

__global__ __launch_bounds__(256)
void fc_k(const float* __restrict__ W, const float* __restrict__ bias,
          const float* __restrict__ in, float* __restrict__ out,
          int O, int D, int mode)
{
    int o = blockIdx.x * 256 + threadIdx.x;
    int b = blockIdx.y;
    if (o >= O) return;
    const float* ib = in + (long)b * D;
    float s = bias[o];
    for (int d = 0; d < D; d++) s += W[(long)o * D + d] * ib[d];
    if (mode == 1) s = 1.f / (1.f + expf(-s));
    out[(long)b * O + o] = s;
}

// y = relu(feat * (1+gamma)), f16 NHWC, 8/thread
__global__ __launch_bounds__(256)
void ymul_h(const f16* __restrict__ feat, const float* __restrict__ gamma,
            f16* __restrict__ y)
{
    long i8 = (blockIdx.x * 256L + threadIdx.x) * 8;
    if (i8 >= 2L * 4096 * 512) return;
    int c0 = (int)(i8 % 512);
    int bb = (int)(i8 / (4096L * 512));
    f16x8 v = *(const f16x8*)&feat[i8];
    f16x8 o;
#pragma unroll
    for (int j = 0; j < 8; j++)
        o[j] = (f16)fmaxf((float)v[j] * (1.f + gamma[bb * 512 + c0 + j]), 0.f);
    *(f16x8*)&y[i8] = o;
}

static inline dim3 hgrid(int M, int N) { return dim3((N + 127) / 128, (M + 63) / 64, 2); }

extern "C" void kernel_launch(void* const* d_in, const int* in_sizes, int n_in,
                              void* d_out, int out_size, void* d_ws, size_t ws_size,
                              hipStream_t stream)
{
    (void)in_sizes; (void)n_in; (void)out_size; (void)ws_size;
    const float* c2  = (const float*)d_in[1];
    const float* c3  = (const float*)d_in[2];
    const float* c4  = (const float*)d_in[3];
    const float* wq4 = (const float*)d_in[7];
    const float* gq4 = (const float*)d_in[8];
    const float* bq4 = (const float*)d_in[9];
    const float* wk4 = (const float*)d_in[10];
    const float* gk4 = (const float*)d_in[11];
    const float* bk4 = (const float*)d_in[12];
    const float* wv4 = (const float*)d_in[13];
    const float* wq3 = (const float*)d_in[14];
    const float* gq3 = (const float*)d_in[15];
    const float* bq3 = (const float*)d_in[16];
    const float* wk3 = (const float*)d_in[17];
    const float* gk3 = (const float*)d_in[18];
    const float* bk3 = (const float*)d_in[19];
    const float* wv3 = (const float*)d_in[20];
    const float* w5  = (const float*)d_in[21];
    const float* g5  = (const float*)d_in[22];
    const float* b5  = (const float*)d_in[23];
    const float* we  = (const float*)d_in[24];
    const float* ge  = (const float*)d_in[25];
    const float* be  = (const float*)d_in[26];
    const float* cw  = (const float*)d_in[27];
    const float* scl = (const float*)d_in[28];
    const float* gK  = (const float*)d_in[29];
    const float* bK  = (const float*)d_in[30];
    const float* wfc = (const float*)d_in[31];
    const float* bfc = (const float*)d_in[32];
    const float* wse = (const float*)d_in[33];
    const float* bse = (const float*)d_in[34];
    const float* w6  = (const float*)d_in[35];
    const float* b6  = (const float*)d_in[36];
    float* outp = (float*)d_out;
    char* ws = (char*)d_ws;

    // ---- workspace (byte offsets), liveness-checked overlays ----
    auto H = [&](long off) { return (f16*)(ws + off); };
    auto F = [&](long off) { return (float*)(ws + off); };
    const long O_wq4h = 0;
    const long O_wk4h = 262144;
    const long O_wv4h = 786432;
    const long O_wq3h = 4980736;
    const long O_wk3h = 5046272;
    const long O_wv3h = 5177344;
    const long O_w5r  = 6225920;
    const long O_weh  = 10944512;
    const long O_cwh  = 11468800;
    const long O_w6h  = 11501568;
    const long O_c3h  = 11665408;
    const long O_Xh   = 11665408;
    const long O_c4h  = 20054016;
    const long O_cku4h= 22151168;
    const long O_v3h  = 22151168;
    const long O_q4h  = 30539776;
    const long O_k4h  = 31064064;
    const long O_v4h  = 31588352;
    const long O_xch  = 30834688;
    const long O_Af   = 31358976;
    const long O_Etp  = 32407552;
    const long O_Ef   = 34504704;
    const long O_asum = 34635776;
    const long O_cc   = 34636032;
    const long O_en   = 34636160;
    const long O_gam  = 34640256;
    const long O_mv   = 34644352;
    const long O_out4h= 35856384;
    const long O_yh   = 35856384;
    const long O_c2h  = 40050688;
    const long O_cku3h= 48439296;
    const long O_feath= 48439296;
    const long O_out3h= 56827904;
    const long O_q3h  = 65216512;
    const long O_k3h  = 66265088;

    float* mv = F(O_mv);

    // ---- conversions ----
    chw2nhwc_k<<<dim3(128, 16, 2), 256, 0, stream>>>(c2, H(O_c2h), 512, 4096);
    chw2nhwc_k<<<dim3(32, 32, 2), 256, 0, stream>>>(c3, H(O_c3h), 1024, 1024);
    chw2nhwc_k<<<dim3(8, 64, 2), 256, 0, stream>>>(c4, H(O_c4h), 2048, 256);
    auto cvt = [&](const float* s, long o, long n) {
        f2h_k<<<(int)((n + 255) / 256), 256, 0, stream>>>(s, H(o), n);
    };
    cvt(wq4, O_wq4h, 128L * 1024); cvt(wk4, O_wk4h, 128L * 2048);
    cvt(wv4, O_wv4h, 1024L * 2048); cvt(wq3, O_wq3h, 64L * 512);
    cvt(wk3, O_wk3h, 64L * 1024); cvt(wv3, O_wv3h, 512L * 1024);
    cvt(we, O_weh, 512L * 512); cvt(cw, O_cwh, 32L * 512);
    cvt(w6, O_w6h, 150L * 512);
    w5r_k<<<9216, 256, 0, stream>>>(w5, H(O_w5r));
    zero_k<<<11, 256, 0, stream>>>(mv, 2816);

    // ---- Stage A: local_up(c3, c4) -> out4h (NHWC 2x1024x1024) ----
    hgemm_k<0><<<hgrid(128, 1024), 256, 0, stream>>>(H(O_wq4h), H(O_c3h), H(O_q4h), nullptr,
        128, 1024, 1024, 1024, 1024L * 1024, 1024L * 128, 0, 0, mv + 0);
    bnapply_k<<<128, 256, 0, stream>>>(H(O_q4h), mv + 0, gq4, bq4, 128, 2L * 1024 * 128, 1.f / 2048.f, 0);
    upsample_h8<<<2048, 256, 0, stream>>>(H(O_c4h), H(O_cku4h), 256, 16, 16, 32, 32);
    hgemm_k<0><<<hgrid(128, 1024), 256, 0, stream>>>(H(O_wk4h), H(O_cku4h), H(O_k4h), nullptr,
        128, 2048, 1024, 2048, 1024L * 2048, 1024L * 128, 0, 0, mv + 256);
    bnapply_k<<<128, 256, 0, stream>>>(H(O_k4h), mv + 256, gk4, bk4, 128, 2L * 1024 * 128, 1.f / 2048.f, 0);
    hgemm_k<0><<<hgrid(1024, 1024), 256, 0, stream>>>(H(O_wv4h), H(O_cku4h), H(O_v4h), nullptr,
        1024, 2048, 1024, 2048, 1024L * 2048, 1024L * 1024, 0, 0, nullptr);
    attpv_k<128, 1024, 32><<<dim3(256, 2), 256, 0, stream>>>(
        H(O_q4h), H(O_k4h), H(O_v4h), H(O_out4h));

    // ---- Stage B: local_up(c2, out4) -> out3h (NHWC 2x4096x512) ----
    hgemm_k<0><<<hgrid(64, 4096), 256, 0, stream>>>(H(O_wq3h), H(O_c2h), H(O_q3h), nullptr,
        64, 512, 4096, 512, 4096L * 512, 4096L * 64, 0, 0, mv + 512);
    bnapply_k<<<256, 256, 0, stream>>>(H(O_q3h), mv + 512, gq3, bq3, 64, 2L * 4096 * 64, 1.f / 8192.f, 0);
    upsample_h8<<<4096, 256, 0, stream>>>(H(O_out4h), H(O_cku3h), 128, 32, 32, 64, 64);
    hgemm_k<0><<<hgrid(64, 4096), 256, 0, stream>>>(H(O_wk3h), H(O_cku3h), H(O_k3h), nullptr,
        64, 1024, 4096, 1024, 4096L * 1024, 4096L * 64, 0, 0, mv + 640);
    bnapply_k<<<256, 256, 0, stream>>>(H(O_k3h), mv + 640, gk3, bk3, 64, 2L * 4096 * 64, 1.f / 8192.f, 0);
    hgemm_k<0><<<hgrid(512, 4096), 256, 0, stream>>>(H(O_wv3h), H(O_cku3h), H(O_v3h), nullptr,
        512, 1024, 4096, 1024, 4096L * 1024, 4096L * 512, 0, 0, nullptr);
    attpv_k<64, 512, 64><<<dim3(1024, 2), 256, 0, stream>>>(
        H(O_q3h), H(O_k3h), H(O_v3h), H(O_out3h));

    // ---- Stage C: feat = relu(BN(conv3x3(out3))) ----
    hgemm_k<1><<<hgrid(512, 4096), 256, 0, stream>>>(H(O_w5r), H(O_out3h), H(O_feath), nullptr,
        512, 4608, 4096, 512, 4096L * 512, 4096L * 512, 64, 64, mv + 768);
    bnapply_k<<<2048, 256, 0, stream>>>(H(O_feath), mv + 768, g5, b5, 512, 2L * 4096 * 512, 1.f / 8192.f, 1);

    // ---- Stage D: enc_module ----
    hgemm_k<0><<<hgrid(512, 4096), 256, 0, stream>>>(H(O_weh), H(O_feath), H(O_Xh), nullptr,
        512, 512, 4096, 512, 4096L * 512, 4096L * 512, 0, 0, mv + 1792);
    bnapply_k<<<2048, 256, 0, stream>>>(H(O_Xh), mv + 1792, ge, be, 512, 2L * 4096 * 512, 1.f / 8192.f, 1);
    hgemm_k<0><<<hgrid(32, 4096), 256, 0, stream>>>(H(O_cwh), H(O_Xh), H(O_xch), nullptr,
        32, 512, 4096, 512, 4096L * 512, 4096L * 32, 0, 0, nullptr);
    cc_k<<<32, 64, 0, stream>>>(cw, F(O_cc), 512);
    assign_h<<<dim3(16, 2), 256, 0, stream>>>(H(O_Xh), H(O_xch), F(O_cc), scl, F(O_Af));
    asum_k<<<dim3(32, 2), 256, 0, stream>>>(F(O_Af), F(O_asum), 4096);
    etg_k<<<dim3(8, 1, 32), 256, 0, stream>>>(F(O_Af), H(O_Xh), F(O_Etp));
    efix2_k<<<128, 256, 0, stream>>>(F(O_Etp), F(O_asum), cw, F(O_Ef));
    bn_stats_k<<<32, 256, 0, stream>>>(F(O_Ef), mv + 2816, 512, 2, 32L * 512);
    en_k<<<4, 256, 0, stream>>>(F(O_Ef), mv + 2816, gK, bK, F(O_en), 512);
    fc_k<<<dim3(2, 2), 256, 0, stream>>>(wfc, bfc, F(O_en), F(O_gam), 512, 512, 1);
    fc_k<<<dim3(1, 2), 256, 0, stream>>>(wse, bse, F(O_en), outp + 1228800, 150, 512, 0);
    ymul_h<<<2048, 256, 0, stream>>>(H(O_feath), F(O_gam), H(O_yh));

    // ---- Stage E: seg = w6 @ y + b6 -> d_out (CHW f32) ----
    hgemm_k<2><<<hgrid(150, 4096), 256, 0, stream>>>(H(O_w6h), H(O_yh), outp, b6,
        150, 512, 4096, 512, 4096L * 512, 150L * 4096, 0, 0, nullptr);
}